// Round 8
// baseline (361.178 us; speedup 1.0000x reference)
//
#include <hip/hip_runtime.h>
#include <hip/hip_fp8.h>
#include <stdint.h>

#define B  32
#define KK 8
#define LQ 128
#define LR 256
#define H  512
#define LL 2176   // LQ + KK*LR

typedef short s16x8 __attribute__((ext_vector_type(8)));
typedef float f32x4 __attribute__((ext_vector_type(4)));
typedef int   i32x8 __attribute__((ext_vector_type(8)));

__device__ __forceinline__ unsigned short f2bf(float f) {
    unsigned int u = __float_as_uint(f);
    unsigned int r = (u + 0x7FFFu + ((u >> 16) & 1u)) >> 16;
    return (unsigned short)r;
}
__device__ __forceinline__ unsigned char f2fp8(float f) {
    __hip_fp8_e4m3 v(f);
    return (unsigned char)v.__x;
}
// pack 2 floats -> 2 fp8 bytes (low word)
__device__ __forceinline__ unsigned int pk_fp8(float a, float b) {
#if __has_builtin(__builtin_amdgcn_cvt_pk_fp8_f32)
    return (unsigned int)__builtin_amdgcn_cvt_pk_fp8_f32(a, b, 0, false) & 0xFFFFu;
#else
    return (unsigned int)f2fp8(a) | ((unsigned int)f2fp8(b) << 8);
#endif
}
__device__ __forceinline__ unsigned int pk_bf16(float a, float b) {
    return (unsigned int)f2bf(a) | ((unsigned int)f2bf(b) << 16);
}
__device__ __forceinline__ void gload16(const void* g, void* l) {
    __builtin_amdgcn_global_load_lds(
        (const __attribute__((address_space(1))) void*)g,
        (__attribute__((address_space(3))) void*)l, 16, 0, 0);
}
__device__ __forceinline__ float fexp2(float x) {
#if __has_builtin(__builtin_amdgcn_exp2f)
    return __builtin_amdgcn_exp2f(x);
#else
    return __expf(x * 0.69314718056f);
#endif
}
__device__ __forceinline__ float frcp(float x) {
#if __has_builtin(__builtin_amdgcn_rcpf)
    return __builtin_amdgcn_rcpf(x);
#else
    return 1.f / x;
#endif
}
__device__ __forceinline__ float fast_tanh(float x) {
    float e = fexp2(x * 2.885390082f);
    return 1.f - 2.f * frcp(1.f + e);
}
#define LOG2E 1.4426950408889634f

// ---------------------------------------------------------------- K0
// Region order: sWs (256) | weights (64) | zero (19) | h_q (256) | h_r (4096).
// Convert blocks: 2048 float4 each; thread owns ADJACENT float4 pairs ->
// 16B bf16 stores + 8B fp8 stores.
#define NQ4 (B * LQ * H / 4)        // 524288
#define NR4 (B * KK * LR * H / 4)   // 8388608
#define NL4 (B * LL / 4)
#define NC4 (B * H / 4)
#define NWB4 (B * LL / 4)
#define SBLK 256
#define WBLK 64
#define ZBLK 19
#define QBLK 256
#define RBLK 4096
#define K0GRID (SBLK + WBLK + ZBLK + QBLK + RBLK)
__global__ __launch_bounds__(256) void k0_convert(
    const float* __restrict__ h_q, const float* __restrict__ h_r,
    const float* __restrict__ U_w, const float* __restrict__ Wqr_w,
    unsigned short* __restrict__ Xb, unsigned short* __restrict__ Uwb,
    unsigned char* __restrict__ Xb8, unsigned char* __restrict__ Wqrb8,
    float* __restrict__ logits, float* __restrict__ out_ct,
    float* __restrict__ wbuf, const float* __restrict__ s_t,
    const float* __restrict__ Ws_w, float* __restrict__ sWs) {
    int t = threadIdx.x;
    int blk = blockIdx.x;
    if (blk < SBLK) {
        // sWs matvec, dispatched first
        int b = blk >> 3, oc = blk & 7;
        __shared__ __align__(16) float sl[H];
        for (int i = t; i < H; i += 256) sl[i] = s_t[b * H + i];
        __syncthreads();
        int o = oc * 64 + (t >> 2);
        int part = t & 3;
        const float4* sl4 = (const float4*)sl;
        const float4* wr4 = (const float4*)(Ws_w + (size_t)o * H);
        float a = 0.f;
#pragma unroll
        for (int ii = 0; ii < 32; ++ii) {
            int i = part + 4 * ii;
            float4 x = sl4[i], y = wr4[i];
            a += x.x * y.x + x.y * y.y + x.z * y.z + x.w * y.w;
        }
        a += __shfl_xor(a, 1);
        a += __shfl_xor(a, 2);
        if (part == 0) sWs[b * H + o] = a;
        return;
    }
    blk -= SBLK;
    if (blk < WBLK) {
        bool isU = (blk < 32);
        unsigned base = (unsigned)(blk & 31) * 2048u;   // f4 units
        const float4* src = isU ? (const float4*)U_w : (const float4*)Wqr_w;
        uint4* dst = isU ? (uint4*)Uwb : (uint4*)((unsigned short*)Xb + 0); // Uwb only; Wqr handled below
        uint4* dstW = (uint4*)((unsigned char*)0);
        (void)dstW;
#pragma unroll
        for (int jj = 0; jj < 4; ++jj) {
            unsigned f4i = base + (unsigned)jj * 512u + 2u * (unsigned)t;
            float4 v0 = src[f4i], v1 = src[f4i + 1];
            uint4 ob;
            ob.x = pk_bf16(v0.x, v0.y); ob.y = pk_bf16(v0.z, v0.w);
            ob.z = pk_bf16(v1.x, v1.y); ob.w = pk_bf16(v1.z, v1.w);
            if (isU) {
                ((uint4*)Uwb)[f4i >> 1] = ob;
            } else {
                // Wqr: fp8 only (k4 consumes Wqrb8)
                uint2 o8;
                o8.x = pk_fp8(v0.x, v0.y) | (pk_fp8(v0.z, v0.w) << 16);
                o8.y = pk_fp8(v1.x, v1.y) | (pk_fp8(v1.z, v1.w) << 16);
                ((uint2*)Wqrb8)[f4i >> 1] = o8;
            }
        }
        return;
    }
    blk -= WBLK;
    if (blk < ZBLK) {
        unsigned zb = (unsigned)blk;
        float4 zero = {0.f, 0.f, 0.f, 0.f};
        float4* lg4 = (float4*)logits;
        float4* ct4 = (float4*)out_ct;
        float4* wb4 = (float4*)wbuf;
#pragma unroll
        for (int j = 0; j < 8; ++j) {
            unsigned z = zb * 2048u + (unsigned)j * 256u + (unsigned)t;
            if (z < NL4) lg4[z] = zero;
            else if (z < NL4 + NC4) ct4[z - NL4] = zero;
            else if (z < NL4 + NC4 + NWB4) wb4[z - NL4 - NC4] = zero;
        }
        return;
    }
    blk -= ZBLK;
    {
        const float4* src; unsigned dstoff;   // dst offset in f4 units within Xb layout
        if (blk < QBLK) {
            unsigned u0 = (unsigned)blk * 2048u;
            unsigned b = (unsigned)blk >> 3;          // 8 blocks per batch
            src = (const float4*)h_q + u0;
            dstoff = b * 278528u + (u0 & 16383u);     // LL*H/4 ; LQ*H/4
        } else {
            unsigned rb = (unsigned)(blk - QBLK);
            unsigned u0 = rb * 2048u;
            unsigned b = rb >> 7;                     // 128 blocks per batch
            src = (const float4*)h_r + u0;
            dstoff = b * 278528u + 16384u + (u0 & 262143u);
        }
        uint4* dstb = (uint4*)Xb;     // index = f4/2
        uint2* dst8 = (uint2*)Xb8;    // index = f4/2
#pragma unroll
        for (int jj = 0; jj < 4; ++jj) {
            unsigned loc = (unsigned)jj * 512u + 2u * (unsigned)t;
            float4 v0 = src[loc], v1 = src[loc + 1];
            unsigned idx = (dstoff + loc) >> 1;
            uint4 ob;
            ob.x = pk_bf16(v0.x, v0.y); ob.y = pk_bf16(v0.z, v0.w);
            ob.z = pk_bf16(v1.x, v1.y); ob.w = pk_bf16(v1.z, v1.w);
            dstb[idx] = ob;
            uint2 o8;
            o8.x = pk_fp8(v0.x, v0.y) | (pk_fp8(v0.z, v0.w) << 16);
            o8.y = pk_fp8(v1.x, v1.y) | (pk_fp8(v1.z, v1.w) << 16);
            dst8[idx] = o8;
        }
    }
}

// ---------------------------------------------------------------- K1: hqU = Xq @ Uw^T -> fp8
__global__ __launch_bounds__(256) void k1_gemm_hqU(
    const unsigned short* __restrict__ Xb, const unsigned short* __restrict__ Uwb,
    unsigned char* __restrict__ hqU8) {
    __shared__ __align__(16) unsigned short As[64 * 64];
    __shared__ __align__(16) unsigned short Bs[128 * 64];
    int tid = threadIdx.x;
    int wave = tid >> 6, lane = tid & 63;
    int quad = lane >> 4, l16 = lane & 15;
    int wr = wave >> 1, wc = wave & 1;
    int g = blockIdx.x;
    int tle = (g & 7) * 32 + (g >> 3);
    int mt = tle >> 2, nt = tle & 3;
    int m0 = mt * 64, n0 = nt * 128;

    const unsigned short* ag[2]; unsigned short* la[2];
    const unsigned short* bg[4]; unsigned short* lb[4];
#pragma unroll
    for (int i = 0; i < 2; ++i) {
        int gg = (wave * 2 + i) * 64 + lane;
        int r = gg >> 3, c = gg & 7, cs = c ^ (r & 7);
        int am = m0 + r;
        ag[i] = Xb + ((size_t)(am >> 7) * LL + (am & 127)) * H + cs * 8;
        la[i] = As + (wave * 2 + i) * 512;
    }
#pragma unroll
    for (int i = 0; i < 4; ++i) {
        int gg = (wave * 4 + i) * 64 + lane;
        int r = gg >> 3, c = gg & 7, cs = c ^ (r & 7);
        bg[i] = Uwb + (size_t)(n0 + r) * H + cs * 8;
        lb[i] = Bs + (wave * 4 + i) * 512;
    }

    f32x4 acc[2][4] = {};
    for (int k0 = 0; k0 < H; k0 += 64) {
#pragma unroll
        for (int i = 0; i < 2; ++i) gload16(ag[i] + k0, la[i]);
#pragma unroll
        for (int i = 0; i < 4; ++i) gload16(bg[i] + k0, lb[i]);
        __syncthreads();
#pragma unroll
        for (int kh = 0; kh < 2; ++kh) {
            s16x8 af[2], bfr[4];
#pragma unroll
            for (int mi = 0; mi < 2; ++mi) {
                int row = wr * 32 + mi * 16 + l16;
                int ch = (kh * 4 + quad) ^ (row & 7);
                af[mi] = *(const s16x8*)&As[(row * 8 + ch) * 8];
            }
#pragma unroll
            for (int ni = 0; ni < 4; ++ni) {
                int row = wc * 64 + ni * 16 + l16;
                int ch = (kh * 4 + quad) ^ (row & 7);
                bfr[ni] = *(const s16x8*)&Bs[(row * 8 + ch) * 8];
            }
#pragma unroll
            for (int mi = 0; mi < 2; ++mi)
#pragma unroll
                for (int ni = 0; ni < 4; ++ni)
                    acc[mi][ni] = __builtin_amdgcn_mfma_f32_16x16x32_bf16(
                        af[mi], bfr[ni], acc[mi][ni], 0, 0, 0);
        }
        __syncthreads();
    }
    // epilogue: lane-pair pack to fp8, even lanes store 2B
#pragma unroll
    for (int mi = 0; mi < 2; ++mi)
#pragma unroll
        for (int ni = 0; ni < 4; ++ni)
#pragma unroll
            for (int i = 0; i < 4; ++i) {
                float v = acc[mi][ni][i];
                float vn = __shfl_xor(v, 1);
                if ((l16 & 1) == 0) {
                    int row = m0 + wr * 32 + mi * 16 + quad * 4 + i;
                    int col = n0 + wc * 64 + ni * 16 + l16;
                    unsigned short pk = (unsigned short)pk_fp8(v, vn);
                    *(unsigned short*)(hqU8 + (size_t)row * H + col) = pk;
                }
            }
}

// ---------------------------------------------------------------- K2: score maxes (MX-fp8)
// 64(q) x 256(r), BK=128 via mfma_scale 16x16x128. grid 512, XCD-swizzled.
__global__ __launch_bounds__(256) void k2_scores(
    const unsigned char* __restrict__ hqU8, const unsigned char* __restrict__ Xb8,
    float* __restrict__ maxq, float* __restrict__ maxr_part) {
    __shared__ __align__(16) unsigned char As[64 * 128];    //  8 KB
    __shared__ __align__(16) unsigned char Bs[256 * 128];   // 32 KB
    __shared__ float redA[64 * 2];
    __shared__ float redB[256 * 2];
    int g = blockIdx.x;
    int tle = (g & 7) * 64 + (g >> 3);
    int qt = tle & 1, k = (tle >> 1) & 7, b = tle >> 4;
    int tid = threadIdx.x;
    int wave = tid >> 6, lane = tid & 63;
    int quad = lane >> 4, l16 = lane & 15;
    int wr = wave >> 1, wc = wave & 1;

    const unsigned char* Ab = hqU8 + (size_t)(b * LQ + qt * 64) * H;
    const unsigned char* Bb = Xb8 + (size_t)(b * LL + LQ + k * LR) * H;

    const unsigned char* ag[2]; unsigned char* la[2];
    const unsigned char* bg[8]; unsigned char* lb[8];
#pragma unroll
    for (int i = 0; i < 2; ++i) {
        int gg = (wave * 2 + i) * 64 + lane;             // 0..511
        int r = gg >> 3, c = gg & 7, cs = c ^ (r & 7);
        ag[i] = Ab + (size_t)r * H + cs * 16;
        la[i] = As + gg * 16;
    }
#pragma unroll
    for (int i = 0; i < 8; ++i) {
        int gg = (wave * 8 + i) * 64 + lane;             // 0..2047
        int r = gg >> 3, c = gg & 7, cs = c ^ (r & 7);
        bg[i] = Bb + (size_t)r * H + cs * 16;
        lb[i] = Bs + gg * 16;
    }

    f32x4 acc[2][8] = {};
    for (int k0 = 0; k0 < H; k0 += 128) {
#pragma unroll
        for (int i = 0; i < 2; ++i) gload16(ag[i] + k0, la[i]);
#pragma unroll
        for (int i = 0; i < 8; ++i) gload16(bg[i] + k0, lb[i]);
        __syncthreads();
        i32x8 af[2];
#pragma unroll
        for (int mi = 0; mi < 2; ++mi) {
            int row = wr * 32 + mi * 16 + l16;
            int xs = row & 7;
            const uint4* rp = (const uint4*)(As + row * 128);
            uint4 lo = rp[(quad * 2) ^ xs];
            uint4 hi = rp[(quad * 2 + 1) ^ xs];
            af[mi][0] = lo.x; af[mi][1] = lo.y; af[mi][2] = lo.z; af[mi][3] = lo.w;
            af[mi][4] = hi.x; af[mi][5] = hi.y; af[mi][6] = hi.z; af[mi][7] = hi.w;
        }
#pragma unroll
        for (int ni = 0; ni < 8; ++ni) {
            int row = wc * 128 + ni * 16 + l16;
            int xs = row & 7;
            const uint4* rp = (const uint4*)(Bs + row * 128);
            uint4 lo = rp[(quad * 2) ^ xs];
            uint4 hi = rp[(quad * 2 + 1) ^ xs];
            i32x8 bfr;
            bfr[0] = lo.x; bfr[1] = lo.y; bfr[2] = lo.z; bfr[3] = lo.w;
            bfr[4] = hi.x; bfr[5] = hi.y; bfr[6] = hi.z; bfr[7] = hi.w;
#pragma unroll
            for (int mi = 0; mi < 2; ++mi)
                acc[mi][ni] = __builtin_amdgcn_mfma_scale_f32_16x16x128_f8f6f4(
                    af[mi], bfr, acc[mi][ni], 0, 0,
                    0, 0x7F7F7F7F, 0, 0x7F7F7F7F);
        }
        __syncthreads();
    }
#pragma unroll
    for (int mi = 0; mi < 2; ++mi)
#pragma unroll
        for (int i = 0; i < 4; ++i) {
            float v = acc[mi][0][i];
#pragma unroll
            for (int ni = 1; ni < 8; ++ni) v = fmaxf(v, acc[mi][ni][i]);
            for (int s = 1; s < 16; s <<= 1) v = fmaxf(v, __shfl_xor(v, s));
            if (l16 == 0) redA[(wr * 32 + mi * 16 + quad * 4 + i) * 2 + wc] = v;
        }
#pragma unroll
    for (int ni = 0; ni < 8; ++ni) {
        float v = acc[0][ni][0];
#pragma unroll
        for (int mi = 0; mi < 2; ++mi)
#pragma unroll
            for (int i = 0; i < 4; ++i) v = fmaxf(v, acc[mi][ni][i]);
        for (int s = 16; s < 64; s <<= 1) v = fmaxf(v, __shfl_xor(v, s));
        if (quad == 0) redB[(wc * 128 + ni * 16 + l16) * 2 + wr] = v;
    }
    __syncthreads();
    size_t bk = (size_t)(b * KK + k);
    if (tid < 64)
        maxq[bk * 128 + qt * 64 + tid] = fmaxf(redA[tid * 2 + 0], redA[tid * 2 + 1]);
    maxr_part[(bk * 2 + qt) * 256 + tid] = fmaxf(redB[tid * 2 + 0], redB[tid * 2 + 1]);
}

// ---------------------------------------------------------------- K3: alphas + wq (grid B*KK)
__global__ __launch_bounds__(256) void k3_alphas(
    const float* __restrict__ maxq, const float* __restrict__ maxr_part,
    const float* __restrict__ r_mask, const float* __restrict__ q_mask,
    float* __restrict__ wbuf) {
    int b = blockIdx.x >> 3, k = blockIdx.x & 7;
    int t = threadIdx.x;
    __shared__ float red[256];
    size_t bk = (size_t)(b * KK + k);
    float vq = -1e30f;
    if (t < 128) vq = fast_tanh(maxq[bk * 128 + t]);
    red[t] = vq; __syncthreads();
    for (int s = 128; s > 0; s >>= 1) { if (t < s) red[t] = fmaxf(red[t], red[t + s]); __syncthreads(); }
    float mxq = red[0]; __syncthreads();
    float eq = (t < 128) ? fexp2((vq - mxq) * LOG2E) : 0.f;
    red[t] = eq; __syncthreads();
    for (int s = 128; s > 0; s >>= 1) { if (t < s) red[t] += red[t + s]; __syncthreads(); }
    float invq = 1.f / red[0]; __syncthreads();
    if (t < 128)
        atomicAdd(&wbuf[b * LL + t], q_mask[b * LQ + t] * eq * invq * 0.125f);
    float vr = fast_tanh(fmaxf(maxr_part[(bk * 2 + 0) * 256 + t],
                               maxr_part[(bk * 2 + 1) * 256 + t]));
    red[t] = vr; __syncthreads();
    for (int s = 128; s > 0; s >>= 1) { if (t < s) red[t] = fmaxf(red[t], red[t + s]); __syncthreads(); }
    float mxr = red[0]; __syncthreads();
    float er = fexp2((vr - mxr) * LOG2E);
    red[t] = er; __syncthreads();
    for (int s = 128; s > 0; s >>= 1) { if (t < s) red[t] += red[t + s]; __syncthreads(); }
    float invr = 1.f / red[0];
    wbuf[b * LL + LQ + k * LR + t] = r_mask[bk * LR + t] * er * invr;
}

// ---------------------------------------------------------------- K4: big GEMM (MX-fp8) + logits
__global__ __launch_bounds__(256) void k4_gemm_logits(
    const unsigned char* __restrict__ Xb8, const unsigned char* __restrict__ Wqrb8,
    const float* __restrict__ sWs, const float* __restrict__ Wqr_b,
    const float* __restrict__ Wc_w, const float* __restrict__ Vr_w,
    const float* __restrict__ wbuf, const float* __restrict__ qr_cov,
    float* __restrict__ logits) {
    __shared__ __align__(16) unsigned char As[128 * 128];  // 16 KB
    __shared__ __align__(16) unsigned char Bs[128 * 128];  // 16 KB
    __shared__ float wrow[128], covrow[128], sWsl[128], biasl[128], wcl[128], vrl[128];
    int tid = threadIdx.x;
    int wave = tid >> 6, lane = tid & 63;
    int quad = lane >> 4, l16 = lane & 15;
    int wr = wave >> 1, wc = wave & 1;
    int g = blockIdx.x;
    int tle = (g & 7) * 272 + (g >> 3);
    int mt = tle >> 2, nt = tle & 3;
    size_t m0 = (size_t)mt * 128;
    int n0 = nt * 128;
    int b = mt / 17;

    if (tid < 128) {
        wrow[tid]   = wbuf[m0 + tid];
        covrow[tid] = qr_cov[m0 + tid];
        sWsl[tid]   = sWs[b * H + n0 + tid];
        biasl[tid]  = Wqr_b[n0 + tid];
        wcl[tid]    = Wc_w[n0 + tid];
        vrl[tid]    = Vr_w[n0 + tid];
    }

    const unsigned char* ag[4]; unsigned char* la[4];
    const unsigned char* bg[4]; unsigned char* lb[4];
#pragma unroll
    for (int i = 0; i < 4; ++i) {
        int gg = (wave * 4 + i) * 64 + lane;
        int r = gg >> 3, c = gg & 7, cs = c ^ (r & 7);
        ag[i] = Xb8 + (m0 + r) * H + cs * 16;
        bg[i] = Wqrb8 + (size_t)(n0 + r) * H + cs * 16;
        la[i] = As + (wave * 4 + i) * 1024;
        lb[i] = Bs + (wave * 4 + i) * 1024;
    }

    f32x4 acc[4][4] = {};
    for (int k0 = 0; k0 < H; k0 += 128) {
#pragma unroll
        for (int i = 0; i < 4; ++i) gload16(ag[i] + k0, la[i]);
#pragma unroll
        for (int i = 0; i < 4; ++i) gload16(bg[i] + k0, lb[i]);
        __syncthreads();
        i32x8 af[4];
#pragma unroll
        for (int mi = 0; mi < 4; ++mi) {
            int row = wr * 64 + mi * 16 + l16;
            int xs = row & 7;
            const uint4* rp = (const uint4*)(As + row * 128);
            uint4 lo = rp[(quad * 2) ^ xs];
            uint4 hi = rp[(quad * 2 + 1) ^ xs];
            af[mi][0] = lo.x; af[mi][1] = lo.y; af[mi][2] = lo.z; af[mi][3] = lo.w;
            af[mi][4] = hi.x; af[mi][5] = hi.y; af[mi][6] = hi.z; af[mi][7] = hi.w;
        }
#pragma unroll
        for (int ni = 0; ni < 4; ++ni) {
            int row = wc * 64 + ni * 16 + l16;
            int xs = row & 7;
            const uint4* rp = (const uint4*)(Bs + row * 128);
            uint4 lo = rp[(quad * 2) ^ xs];
            uint4 hi = rp[(quad * 2 + 1) ^ xs];
            i32x8 bfr;
            bfr[0] = lo.x; bfr[1] = lo.y; bfr[2] = lo.z; bfr[3] = lo.w;
            bfr[4] = hi.x; bfr[5] = hi.y; bfr[6] = hi.z; bfr[7] = hi.w;
#pragma unroll
            for (int mi = 0; mi < 4; ++mi)
                acc[mi][ni] = __builtin_amdgcn_mfma_scale_f32_16x16x128_f8f6f4(
                    af[mi], bfr, acc[mi][ni], 0, 0,
                    0, 0x7F7F7F7F, 0, 0x7F7F7F7F);
        }
        __syncthreads();
    }
#pragma unroll
    for (int mi = 0; mi < 4; ++mi)
#pragma unroll
        for (int i = 0; i < 4; ++i) {
            int rl = wr * 64 + mi * 16 + quad * 4 + i;
            float wv = wrow[rl], cv = covrow[rl];
            float lsum = 0.f;
#pragma unroll
            for (int ni = 0; ni < 4; ++ni) {
                int ol = wc * 64 + ni * 16 + l16;
                float dec = sWsl[ol] + wv * acc[mi][ni][i] + biasl[ol] + cv * wcl[ol];
                lsum += vrl[ol] * fast_tanh(dec);
            }
            for (int s = 1; s < 16; s <<= 1) lsum += __shfl_xor(lsum, s);
            if (l16 == 0) atomicAdd(&logits[m0 + rl], lsum);
        }
}

// ---------------------------------------------------------------- K5a: softmax -> a, new_cov, coef
__global__ __launch_bounds__(256) void k5a_softmax(
    const float* __restrict__ logits, const float* __restrict__ q_mask,
    const float* __restrict__ r_mask, const float* __restrict__ qr_cov,
    const float* __restrict__ wbuf, float* __restrict__ out,
    float* __restrict__ coef) {
    int b = blockIdx.x, t = threadIdx.x;
    __shared__ float lg[LL];
    __shared__ float red[256];
    float mx = -1e30f;
    for (int l = t; l < LL; l += 256) {
        float v = logits[b * LL + l];
        lg[l] = v;
        mx = fmaxf(mx, v);
    }
    red[t] = mx; __syncthreads();
    for (int s = 128; s > 0; s >>= 1) { if (t < s) red[t] = fmaxf(red[t], red[t + s]); __syncthreads(); }
    mx = red[0]; __syncthreads();
    float sum = 0.f;
    for (int l = t; l < LL; l += 256) {
        float e = fexp2((lg[l] - mx) * LOG2E);
        float m = (l < LQ) ? q_mask[b * LQ + l] : r_mask[b * (KK * LR) + l - LQ];
        float em = e * m;
        lg[l] = em;
        sum += em;
    }
    red[t] = sum; __syncthreads();
    for (int s = 128; s > 0; s >>= 1) { if (t < s) red[t] += red[t + s]; __syncthreads(); }
    float inv = 1.f / red[0];
    __syncthreads();
    float* aout = out + B * H + (size_t)b * LL;
    float* cov  = out + B * H + (size_t)B * LL + (size_t)b * LL;
    for (int l = t; l < LL; l += 256) {
        float a = lg[l] * inv;
        aout[l] = a;
        cov[l] = qr_cov[b * LL + l] + a;
        coef[b * LL + l] = a * wbuf[b * LL + l];
    }
}

// ---------------------------------------------------------------- K5b: c_t
__global__ __launch_bounds__(256) void k5b_ct(
    const unsigned short* __restrict__ Xb, const float* __restrict__ coef,
    float* __restrict__ out) {
    int b = blockIdx.x / 34, chunk = blockIdx.x % 34;
    int t = threadIdx.x;
    int l0 = chunk * 64;
    __shared__ float cl[64];
    __shared__ float red[4][512];
    if (t < 64) cl[t] = coef[b * LL + l0 + t];
    __syncthreads();
    int rr = t >> 6, lane = t & 63, cc = lane * 8;
    float a[8] = {};
    const unsigned short* xp = Xb + ((size_t)b * LL + l0) * H;
    for (int l = rr; l < 64; l += 4) {
        float c = cl[l];
        uint4 u4 = *(const uint4*)(xp + (size_t)l * H + cc);
        a[0] += c * __uint_as_float(u4.x << 16);
        a[1] += c * __uint_as_float(u4.x & 0xffff0000u);
        a[2] += c * __uint_as_float(u4.y << 16);
        a[3] += c * __uint_as_float(u4.y & 0xffff0000u);
        a[4] += c * __uint_as_float(u4.z << 16);
        a[5] += c * __uint_as_float(u4.z & 0xffff0000u);
        a[6] += c * __uint_as_float(u4.w << 16);
        a[7] += c * __uint_as_float(u4.w & 0xffff0000u);
    }
#pragma unroll
    for (int j = 0; j < 8; ++j) red[rr][cc + j] = a[j];
    __syncthreads();
    int col = t * 2;
    float s0 = red[0][col] + red[1][col] + red[2][col] + red[3][col];
    float s1 = red[0][col + 1] + red[1][col + 1] + red[2][col + 1] + red[3][col + 1];
    atomicAdd(&out[b * H + col], s0);
    atomicAdd(&out[b * H + col + 1], s1);
}

// ================================================================ launch
extern "C" void kernel_launch(void* const* d_in, const int* in_sizes, int n_in,
                              void* d_out, int out_size, void* d_ws, size_t ws_size,
                              hipStream_t stream) {
    (void)in_sizes; (void)n_in; (void)out_size; (void)ws_size;
    const float* h_q    = (const float*)d_in[0];
    const float* q_mask = (const float*)d_in[1];
    const float* h_r    = (const float*)d_in[2];
    const float* r_mask = (const float*)d_in[3];
    const float* s_t    = (const float*)d_in[4];
    const float* qr_cov = (const float*)d_in[5];
    const float* U_w    = (const float*)d_in[6];
    const float* Wc_w   = (const float*)d_in[7];
    const float* Ws_w   = (const float*)d_in[8];
    const float* Wqr_w  = (const float*)d_in[9];
    const float* Wqr_b  = (const float*)d_in[10];
    const float* Vr_w   = (const float*)d_in[11];
    float* out = (float*)d_out;

    char* p = (char*)d_ws;
    unsigned short* Xb    = (unsigned short*)p; p += (size_t)B * LL * H * 2;
    unsigned char*  Xb8   = (unsigned char*)p;  p += (size_t)B * LL * H;
    unsigned short* Uwb   = (unsigned short*)p; p += (size_t)H * H * 2;
    unsigned char*  Wqrb8 = (unsigned char*)p;  p += (size_t)H * H;
    unsigned char*  hqU8  = (unsigned char*)p;  p += (size_t)B * LQ * H;
    float* sWs       = (float*)p; p += (size_t)B * H * 4;
    float* maxq      = (float*)p; p += (size_t)B * KK * 128 * 4;
    float* maxr_part = (float*)p; p += (size_t)B * KK * 2 * 256 * 4;
    float* wbuf      = (float*)p; p += (size_t)B * LL * 4;
    float* logits    = (float*)p; p += (size_t)B * LL * 4;
    float* coef      = (float*)p; p += (size_t)B * LL * 4;

    k0_convert<<<K0GRID, 256, 0, stream>>>(h_q, h_r, U_w, Wqr_w, Xb, Uwb,
                                           Xb8, Wqrb8, logits, out, wbuf,
                                           s_t, Ws_w, sWs);
    k1_gemm_hqU<<<256, 256, 0, stream>>>(Xb, Uwb, hqU8);
    k2_scores<<<512, 256, 0, stream>>>(hqU8, Xb8, maxq, maxr_part);
    k3_alphas<<<B * KK, 256, 0, stream>>>(maxq, maxr_part, r_mask, q_mask, wbuf);
    k4_gemm_logits<<<2176, 256, 0, stream>>>(
        Xb8, Wqrb8, sWs, Wqr_b, Wc_w, Vr_w, wbuf, qr_cov, logits);
    k5a_softmax<<<B, 256, 0, stream>>>(logits, q_mask, r_mask, qr_cov, wbuf, out, coef);
    k5b_ct<<<B * 34, 256, 0, stream>>>(Xb, coef, out);
}

// Round 9
// 344.012 us; speedup vs baseline: 1.0499x; 1.0499x over previous
//
#include <hip/hip_runtime.h>
#include <hip/hip_fp8.h>
#include <stdint.h>

#define B  32
#define KK 8
#define LQ 128
#define LR 256
#define H  512
#define LL 2176   // LQ + KK*LR

typedef short s16x8 __attribute__((ext_vector_type(8)));
typedef float f32x4 __attribute__((ext_vector_type(4)));
typedef int   i32x8 __attribute__((ext_vector_type(8)));

__device__ __forceinline__ unsigned short f2bf(float f) {
    unsigned int u = __float_as_uint(f);
    unsigned int r = (u + 0x7FFFu + ((u >> 16) & 1u)) >> 16;
    return (unsigned short)r;
}
__device__ __forceinline__ unsigned char f2fp8(float f) {
    __hip_fp8_e4m3 v(f);
    return (unsigned char)v.__x;
}
// pack 4 floats -> 4 fp8 bytes
__device__ __forceinline__ unsigned int pk_fp8x4(float a, float b, float c, float d) {
#if __has_builtin(__builtin_amdgcn_cvt_pk_fp8_f32)
    int w = __builtin_amdgcn_cvt_pk_fp8_f32(a, b, 0, false);
    w = __builtin_amdgcn_cvt_pk_fp8_f32(c, d, w, true);
    return (unsigned int)w;
#else
    return (unsigned int)f2fp8(a) | ((unsigned int)f2fp8(b) << 8) |
           ((unsigned int)f2fp8(c) << 16) | ((unsigned int)f2fp8(d) << 24);
#endif
}
__device__ __forceinline__ unsigned int pk_bf16(float a, float b) {
    return (unsigned int)f2bf(a) | ((unsigned int)f2bf(b) << 16);
}
__device__ __forceinline__ void gload16(const void* g, void* l) {
    __builtin_amdgcn_global_load_lds(
        (const __attribute__((address_space(1))) void*)g,
        (__attribute__((address_space(3))) void*)l, 16, 0, 0);
}
__device__ __forceinline__ float fexp2(float x) {
#if __has_builtin(__builtin_amdgcn_exp2f)
    return __builtin_amdgcn_exp2f(x);
#else
    return __expf(x * 0.69314718056f);
#endif
}
__device__ __forceinline__ float frcp(float x) {
#if __has_builtin(__builtin_amdgcn_rcpf)
    return __builtin_amdgcn_rcpf(x);
#else
    return 1.f / x;
#endif
}
__device__ __forceinline__ float fast_tanh(float x) {
    float e = fexp2(x * 2.885390082f);
    return 1.f - 2.f * frcp(1.f + e);
}
#define LOG2E 1.4426950408889634f

// ---------------------------------------------------------------- K0
// Regions: sWs (256) | weights (64) | zero (19) | h_q (256) | h_r (4096).
// h_q -> dense Xq bf16 + Xb8 fp8 ; h_r -> Xb8 fp8 only.
#define NL4 (B * LL / 4)
#define NC4 (B * H / 4)
#define NWB4 (B * LL / 4)
#define SBLK 256
#define WBLK 64
#define ZBLK 19
#define QBLK 256
#define RBLK 4096
#define K0GRID (SBLK + WBLK + ZBLK + QBLK + RBLK)
__global__ __launch_bounds__(256) void k0_convert(
    const float* __restrict__ h_q, const float* __restrict__ h_r,
    const float* __restrict__ U_w, const float* __restrict__ Wqr_w,
    unsigned short* __restrict__ Xq, unsigned short* __restrict__ Uwb,
    unsigned char* __restrict__ Xb8, unsigned char* __restrict__ Wqrb8,
    float* __restrict__ logits, float* __restrict__ out_ct,
    float* __restrict__ wbuf, const float* __restrict__ s_t,
    const float* __restrict__ Ws_w, float* __restrict__ sWs) {
    int t = threadIdx.x;
    int blk = blockIdx.x;
    if (blk < SBLK) {
        int b = blk >> 3, oc = blk & 7;
        __shared__ __align__(16) float sl[H];
        for (int i = t; i < H; i += 256) sl[i] = s_t[b * H + i];
        __syncthreads();
        int o = oc * 64 + (t >> 2);
        int part = t & 3;
        const float4* sl4 = (const float4*)sl;
        const float4* wr4 = (const float4*)(Ws_w + (size_t)o * H);
        float a = 0.f;
#pragma unroll
        for (int ii = 0; ii < 32; ++ii) {
            int i = part + 4 * ii;
            float4 x = sl4[i], y = wr4[i];
            a += x.x * y.x + x.y * y.y + x.z * y.z + x.w * y.w;
        }
        a += __shfl_xor(a, 1);
        a += __shfl_xor(a, 2);
        if (part == 0) sWs[b * H + o] = a;
        return;
    }
    blk -= SBLK;
    if (blk < WBLK) {
        bool isU = (blk < 32);
        unsigned base = (unsigned)(blk & 31) * 2048u;   // f4 units
        const float4* src = isU ? (const float4*)U_w : (const float4*)Wqr_w;
#pragma unroll
        for (int jj = 0; jj < 4; ++jj) {
            unsigned f4i = base + (unsigned)jj * 512u + 2u * (unsigned)t;
            float4 v0 = src[f4i], v1 = src[f4i + 1];
            if (isU) {
                uint4 ob;
                ob.x = pk_bf16(v0.x, v0.y); ob.y = pk_bf16(v0.z, v0.w);
                ob.z = pk_bf16(v1.x, v1.y); ob.w = pk_bf16(v1.z, v1.w);
                ((uint4*)Uwb)[f4i >> 1] = ob;
            } else {
                uint2 o8;
                o8.x = pk_fp8x4(v0.x, v0.y, v0.z, v0.w);
                o8.y = pk_fp8x4(v1.x, v1.y, v1.z, v1.w);
                ((uint2*)Wqrb8)[f4i >> 1] = o8;
            }
        }
        return;
    }
    blk -= WBLK;
    if (blk < ZBLK) {
        unsigned zb = (unsigned)blk;
        float4 zero = {0.f, 0.f, 0.f, 0.f};
        float4* lg4 = (float4*)logits;
        float4* ct4 = (float4*)out_ct;
        float4* wb4 = (float4*)wbuf;
#pragma unroll
        for (int j = 0; j < 8; ++j) {
            unsigned z = zb * 2048u + (unsigned)j * 256u + (unsigned)t;
            if (z < NL4) lg4[z] = zero;
            else if (z < NL4 + NC4) ct4[z - NL4] = zero;
            else if (z < NL4 + NC4 + NWB4) wb4[z - NL4 - NC4] = zero;
        }
        return;
    }
    blk -= ZBLK;
    if (blk < QBLK) {
        unsigned u0 = (unsigned)blk * 2048u;
        unsigned b = (unsigned)blk >> 3;              // 8 blocks per batch
        const float4* src = (const float4*)h_q + u0;
#pragma unroll
        for (int jj = 0; jj < 4; ++jj) {
            unsigned loc = (unsigned)jj * 512u + 2u * (unsigned)t;
            float4 v0 = src[loc], v1 = src[loc + 1];
            uint4 ob;
            ob.x = pk_bf16(v0.x, v0.y); ob.y = pk_bf16(v0.z, v0.w);
            ob.z = pk_bf16(v1.x, v1.y); ob.w = pk_bf16(v1.z, v1.w);
            ((uint4*)Xq)[(u0 + loc) >> 1] = ob;       // dense [B*LQ, H]
            uint2 o8;
            o8.x = pk_fp8x4(v0.x, v0.y, v0.z, v0.w);
            o8.y = pk_fp8x4(v1.x, v1.y, v1.z, v1.w);
            unsigned f8off = b * 278528u + ((u0 + loc) & 16383u);  // LL*H/4, LQ*H/4
            ((uint2*)Xb8)[f8off >> 1] = o8;
        }
        return;
    }
    {
        unsigned rb = (unsigned)(blk - QBLK);
        unsigned u0 = rb * 2048u;
        unsigned b = rb >> 7;                         // 128 blocks per batch
        const float4* src = (const float4*)h_r + u0;
#pragma unroll
        for (int jj = 0; jj < 4; ++jj) {
            unsigned loc = (unsigned)jj * 512u + 2u * (unsigned)t;
            float4 v0 = src[loc], v1 = src[loc + 1];
            uint2 o8;
            o8.x = pk_fp8x4(v0.x, v0.y, v0.z, v0.w);
            o8.y = pk_fp8x4(v1.x, v1.y, v1.z, v1.w);
            unsigned f8off = b * 278528u + 16384u + ((u0 + loc) & 262143u);
            ((uint2*)Xb8)[f8off >> 1] = o8;
        }
    }
}

// ---------------------------------------------------------------- K1: hqU = Xq @ Uw^T -> fp8
__global__ __launch_bounds__(256) void k1_gemm_hqU(
    const unsigned short* __restrict__ Xq, const unsigned short* __restrict__ Uwb,
    unsigned char* __restrict__ hqU8) {
    __shared__ __align__(16) unsigned short As[64 * 64];
    __shared__ __align__(16) unsigned short Bs[128 * 64];
    int tid = threadIdx.x;
    int wave = tid >> 6, lane = tid & 63;
    int quad = lane >> 4, l16 = lane & 15;
    int wr = wave >> 1, wc = wave & 1;
    int g = blockIdx.x;
    int tle = (g & 7) * 32 + (g >> 3);
    int mt = tle >> 2, nt = tle & 3;
    int m0 = mt * 64, n0 = nt * 128;

    const unsigned short* ag[2]; unsigned short* la[2];
    const unsigned short* bg[4]; unsigned short* lb[4];
#pragma unroll
    for (int i = 0; i < 2; ++i) {
        int gg = (wave * 2 + i) * 64 + lane;
        int r = gg >> 3, c = gg & 7, cs = c ^ (r & 7);
        ag[i] = Xq + (size_t)(m0 + r) * H + cs * 8;
        la[i] = As + (wave * 2 + i) * 512;
    }
#pragma unroll
    for (int i = 0; i < 4; ++i) {
        int gg = (wave * 4 + i) * 64 + lane;
        int r = gg >> 3, c = gg & 7, cs = c ^ (r & 7);
        bg[i] = Uwb + (size_t)(n0 + r) * H + cs * 8;
        lb[i] = Bs + (wave * 4 + i) * 512;
    }

    f32x4 acc[2][4] = {};
    for (int k0 = 0; k0 < H; k0 += 64) {
#pragma unroll
        for (int i = 0; i < 2; ++i) gload16(ag[i] + k0, la[i]);
#pragma unroll
        for (int i = 0; i < 4; ++i) gload16(bg[i] + k0, lb[i]);
        __syncthreads();
#pragma unroll
        for (int kh = 0; kh < 2; ++kh) {
            s16x8 af[2], bfr[4];
#pragma unroll
            for (int mi = 0; mi < 2; ++mi) {
                int row = wr * 32 + mi * 16 + l16;
                int ch = (kh * 4 + quad) ^ (row & 7);
                af[mi] = *(const s16x8*)&As[(row * 8 + ch) * 8];
            }
#pragma unroll
            for (int ni = 0; ni < 4; ++ni) {
                int row = wc * 64 + ni * 16 + l16;
                int ch = (kh * 4 + quad) ^ (row & 7);
                bfr[ni] = *(const s16x8*)&Bs[(row * 8 + ch) * 8];
            }
#pragma unroll
            for (int mi = 0; mi < 2; ++mi)
#pragma unroll
                for (int ni = 0; ni < 4; ++ni)
                    acc[mi][ni] = __builtin_amdgcn_mfma_f32_16x16x32_bf16(
                        af[mi], bfr[ni], acc[mi][ni], 0, 0, 0);
        }
        __syncthreads();
    }
#pragma unroll
    for (int mi = 0; mi < 2; ++mi)
#pragma unroll
        for (int ni = 0; ni < 4; ++ni)
#pragma unroll
            for (int i = 0; i < 4; ++i) {
                float v = acc[mi][ni][i];
                float vn = __shfl_xor(v, 1);
                if ((l16 & 1) == 0) {
                    int row = m0 + wr * 32 + mi * 16 + quad * 4 + i;
                    int col = n0 + wc * 64 + ni * 16 + l16;
                    unsigned short pk = (unsigned short)
                        (pk_fp8x4(v, vn, 0.f, 0.f) & 0xFFFFu);
                    *(unsigned short*)(hqU8 + (size_t)row * H + col) = pk;
                }
            }
}

// ---------------------------------------------------------------- K2: score maxes (MX-fp8)
__global__ __launch_bounds__(256) void k2_scores(
    const unsigned char* __restrict__ hqU8, const unsigned char* __restrict__ Xb8,
    float* __restrict__ maxq, float* __restrict__ maxr_part) {
    __shared__ __align__(16) unsigned char As[64 * 128];
    __shared__ __align__(16) unsigned char Bs[256 * 128];
    __shared__ float redA[64 * 2];
    __shared__ float redB[256 * 2];
    int g = blockIdx.x;
    int tle = (g & 7) * 64 + (g >> 3);
    int qt = tle & 1, k = (tle >> 1) & 7, b = tle >> 4;
    int tid = threadIdx.x;
    int wave = tid >> 6, lane = tid & 63;
    int quad = lane >> 4, l16 = lane & 15;
    int wr = wave >> 1, wc = wave & 1;

    const unsigned char* Ab = hqU8 + (size_t)(b * LQ + qt * 64) * H;
    const unsigned char* Bb = Xb8 + (size_t)(b * LL + LQ + k * LR) * H;

    const unsigned char* ag[2]; unsigned char* la[2];
    const unsigned char* bg[8]; unsigned char* lb[8];
#pragma unroll
    for (int i = 0; i < 2; ++i) {
        int gg = (wave * 2 + i) * 64 + lane;
        int r = gg >> 3, c = gg & 7, cs = c ^ (r & 7);
        ag[i] = Ab + (size_t)r * H + cs * 16;
        la[i] = As + gg * 16;
    }
#pragma unroll
    for (int i = 0; i < 8; ++i) {
        int gg = (wave * 8 + i) * 64 + lane;
        int r = gg >> 3, c = gg & 7, cs = c ^ (r & 7);
        bg[i] = Bb + (size_t)r * H + cs * 16;
        lb[i] = Bs + gg * 16;
    }

    f32x4 acc[2][8] = {};
    for (int k0 = 0; k0 < H; k0 += 128) {
#pragma unroll
        for (int i = 0; i < 2; ++i) gload16(ag[i] + k0, la[i]);
#pragma unroll
        for (int i = 0; i < 8; ++i) gload16(bg[i] + k0, lb[i]);
        __syncthreads();
        i32x8 af[2];
#pragma unroll
        for (int mi = 0; mi < 2; ++mi) {
            int row = wr * 32 + mi * 16 + l16;
            int xs = row & 7;
            const uint4* rp = (const uint4*)(As + row * 128);
            uint4 lo = rp[(quad * 2) ^ xs];
            uint4 hi = rp[(quad * 2 + 1) ^ xs];
            af[mi][0] = lo.x; af[mi][1] = lo.y; af[mi][2] = lo.z; af[mi][3] = lo.w;
            af[mi][4] = hi.x; af[mi][5] = hi.y; af[mi][6] = hi.z; af[mi][7] = hi.w;
        }
#pragma unroll
        for (int ni = 0; ni < 8; ++ni) {
            int row = wc * 128 + ni * 16 + l16;
            int xs = row & 7;
            const uint4* rp = (const uint4*)(Bs + row * 128);
            uint4 lo = rp[(quad * 2) ^ xs];
            uint4 hi = rp[(quad * 2 + 1) ^ xs];
            i32x8 bfr;
            bfr[0] = lo.x; bfr[1] = lo.y; bfr[2] = lo.z; bfr[3] = lo.w;
            bfr[4] = hi.x; bfr[5] = hi.y; bfr[6] = hi.z; bfr[7] = hi.w;
#pragma unroll
            for (int mi = 0; mi < 2; ++mi)
                acc[mi][ni] = __builtin_amdgcn_mfma_scale_f32_16x16x128_f8f6f4(
                    af[mi], bfr, acc[mi][ni], 0, 0,
                    0, 0x7F7F7F7F, 0, 0x7F7F7F7F);
        }
        __syncthreads();
    }
#pragma unroll
    for (int mi = 0; mi < 2; ++mi)
#pragma unroll
        for (int i = 0; i < 4; ++i) {
            float v = acc[mi][0][i];
#pragma unroll
            for (int ni = 1; ni < 8; ++ni) v = fmaxf(v, acc[mi][ni][i]);
            for (int s = 1; s < 16; s <<= 1) v = fmaxf(v, __shfl_xor(v, s));
            if (l16 == 0) redA[(wr * 32 + mi * 16 + quad * 4 + i) * 2 + wc] = v;
        }
#pragma unroll
    for (int ni = 0; ni < 8; ++ni) {
        float v = acc[0][ni][0];
#pragma unroll
        for (int mi = 0; mi < 2; ++mi)
#pragma unroll
            for (int i = 0; i < 4; ++i) v = fmaxf(v, acc[mi][ni][i]);
        for (int s = 16; s < 64; s <<= 1) v = fmaxf(v, __shfl_xor(v, s));
        if (quad == 0) redB[(wc * 128 + ni * 16 + l16) * 2 + wr] = v;
    }
    __syncthreads();
    size_t bk = (size_t)(b * KK + k);
    if (tid < 64)
        maxq[bk * 128 + qt * 64 + tid] = fmaxf(redA[tid * 2 + 0], redA[tid * 2 + 1]);
    maxr_part[(bk * 2 + qt) * 256 + tid] = fmaxf(redB[tid * 2 + 0], redB[tid * 2 + 1]);
}

// ---------------------------------------------------------------- K3: alphas + wq
__global__ __launch_bounds__(256) void k3_alphas(
    const float* __restrict__ maxq, const float* __restrict__ maxr_part,
    const float* __restrict__ r_mask, const float* __restrict__ q_mask,
    float* __restrict__ wbuf) {
    int b = blockIdx.x >> 3, k = blockIdx.x & 7;
    int t = threadIdx.x;
    __shared__ float red[256];
    size_t bk = (size_t)(b * KK + k);
    float vq = -1e30f;
    if (t < 128) vq = fast_tanh(maxq[bk * 128 + t]);
    red[t] = vq; __syncthreads();
    for (int s = 128; s > 0; s >>= 1) { if (t < s) red[t] = fmaxf(red[t], red[t + s]); __syncthreads(); }
    float mxq = red[0]; __syncthreads();
    float eq = (t < 128) ? fexp2((vq - mxq) * LOG2E) : 0.f;
    red[t] = eq; __syncthreads();
    for (int s = 128; s > 0; s >>= 1) { if (t < s) red[t] += red[t + s]; __syncthreads(); }
    float invq = 1.f / red[0]; __syncthreads();
    if (t < 128)
        atomicAdd(&wbuf[b * LL + t], q_mask[b * LQ + t] * eq * invq * 0.125f);
    float vr = fast_tanh(fmaxf(maxr_part[(bk * 2 + 0) * 256 + t],
                               maxr_part[(bk * 2 + 1) * 256 + t]));
    red[t] = vr; __syncthreads();
    for (int s = 128; s > 0; s >>= 1) { if (t < s) red[t] = fmaxf(red[t], red[t + s]); __syncthreads(); }
    float mxr = red[0]; __syncthreads();
    float er = fexp2((vr - mxr) * LOG2E);
    red[t] = er; __syncthreads();
    for (int s = 128; s > 0; s >>= 1) { if (t < s) red[t] += red[t + s]; __syncthreads(); }
    float invr = 1.f / red[0];
    wbuf[b * LL + LQ + k * LR + t] = r_mask[bk * LR + t] * er * invr;
}

// ---------------------------------------------------------------- K4: GEMM (MX-fp8) + logits
// 64x64 tiles, BK=128; grid 8704 = 1088 mt x 8 nt, XCD-swizzled (8 nt consecutive).
// Small tiles + low VGPR -> high occupancy; bubbles hidden across many blocks.
__global__ __launch_bounds__(256, 4) void k4_gemm_logits(
    const unsigned char* __restrict__ Xb8, const unsigned char* __restrict__ Wqrb8,
    const float* __restrict__ sWs, const float* __restrict__ Wqr_b,
    const float* __restrict__ Wc_w, const float* __restrict__ Vr_w,
    const float* __restrict__ wbuf, const float* __restrict__ qr_cov,
    float* __restrict__ logits) {
    __shared__ __align__(16) unsigned char As[64 * 128];  // 8 KB
    __shared__ __align__(16) unsigned char Bs[64 * 128];  // 8 KB
    __shared__ float wrow[64], covrow[64], sWsl[64], biasl[64], wcl[64], vrl[64];
    int tid = threadIdx.x;
    int wave = tid >> 6, lane = tid & 63;
    int quad = lane >> 4, l16 = lane & 15;
    int wr = wave >> 1, wc = wave & 1;
    int g = blockIdx.x;
    int tle = (g & 7) * 1088 + (g >> 3);
    int mt = tle >> 3, nt = tle & 7;
    size_t m0 = (size_t)mt * 64;      // 34 tiles per batch, never crosses
    int n0 = nt * 64;
    int b = mt / 34;

    if (tid < 64) {
        wrow[tid]   = wbuf[m0 + tid];
        covrow[tid] = qr_cov[m0 + tid];
        sWsl[tid]   = sWs[b * H + n0 + tid];
        biasl[tid]  = Wqr_b[n0 + tid];
        wcl[tid]    = Wc_w[n0 + tid];
        vrl[tid]    = Vr_w[n0 + tid];
    }

    const unsigned char* ag[2]; unsigned char* la[2];
    const unsigned char* bg[2]; unsigned char* lb[2];
#pragma unroll
    for (int i = 0; i < 2; ++i) {
        int gg = (wave * 2 + i) * 64 + lane;            // 0..511
        int r = gg >> 3, c = gg & 7, cs = c ^ (r & 7);
        ag[i] = Xb8 + (m0 + r) * H + cs * 16;
        bg[i] = Wqrb8 + (size_t)(n0 + r) * H + cs * 16;
        la[i] = As + gg * 16;
        lb[i] = Bs + gg * 16;
    }

    f32x4 acc[2][2] = {};
    for (int k0 = 0; k0 < H; k0 += 128) {
#pragma unroll
        for (int i = 0; i < 2; ++i) gload16(ag[i] + k0, la[i]);
#pragma unroll
        for (int i = 0; i < 2; ++i) gload16(bg[i] + k0, lb[i]);
        __syncthreads();
        i32x8 af[2];
#pragma unroll
        for (int mi = 0; mi < 2; ++mi) {
            int row = wr * 32 + mi * 16 + l16;
            int xs = row & 7;
            const uint4* rp = (const uint4*)(As + row * 128);
            uint4 lo = rp[(quad * 2) ^ xs];
            uint4 hi = rp[(quad * 2 + 1) ^ xs];
            af[mi][0] = lo.x; af[mi][1] = lo.y; af[mi][2] = lo.z; af[mi][3] = lo.w;
            af[mi][4] = hi.x; af[mi][5] = hi.y; af[mi][6] = hi.z; af[mi][7] = hi.w;
        }
#pragma unroll
        for (int ni = 0; ni < 2; ++ni) {
            int row = wc * 32 + ni * 16 + l16;
            int xs = row & 7;
            const uint4* rp = (const uint4*)(Bs + row * 128);
            uint4 lo = rp[(quad * 2) ^ xs];
            uint4 hi = rp[(quad * 2 + 1) ^ xs];
            i32x8 bfr;
            bfr[0] = lo.x; bfr[1] = lo.y; bfr[2] = lo.z; bfr[3] = lo.w;
            bfr[4] = hi.x; bfr[5] = hi.y; bfr[6] = hi.z; bfr[7] = hi.w;
#pragma unroll
            for (int mi = 0; mi < 2; ++mi)
                acc[mi][ni] = __builtin_amdgcn_mfma_scale_f32_16x16x128_f8f6f4(
                    af[mi], bfr, acc[mi][ni], 0, 0,
                    0, 0x7F7F7F7F, 0, 0x7F7F7F7F);
        }
        __syncthreads();
    }
#pragma unroll
    for (int mi = 0; mi < 2; ++mi)
#pragma unroll
        for (int i = 0; i < 4; ++i) {
            int rl = wr * 32 + mi * 16 + quad * 4 + i;
            float wv = wrow[rl], cv = covrow[rl];
            float lsum = 0.f;
#pragma unroll
            for (int ni = 0; ni < 2; ++ni) {
                int ol = wc * 32 + ni * 16 + l16;
                float dec = sWsl[ol] + wv * acc[mi][ni][i] + biasl[ol] + cv * wcl[ol];
                lsum += vrl[ol] * fast_tanh(dec);
            }
            for (int s = 1; s < 16; s <<= 1) lsum += __shfl_xor(lsum, s);
            if (l16 == 0) atomicAdd(&logits[m0 + rl], lsum);
        }
}

// ---------------------------------------------------------------- K5a: softmax
__global__ __launch_bounds__(256) void k5a_softmax(
    const float* __restrict__ logits, const float* __restrict__ q_mask,
    const float* __restrict__ r_mask, const float* __restrict__ qr_cov,
    const float* __restrict__ wbuf, float* __restrict__ out,
    float* __restrict__ coef) {
    int b = blockIdx.x, t = threadIdx.x;
    __shared__ float lg[LL];
    __shared__ float red[256];
    float mx = -1e30f;
    for (int l = t; l < LL; l += 256) {
        float v = logits[b * LL + l];
        lg[l] = v;
        mx = fmaxf(mx, v);
    }
    red[t] = mx; __syncthreads();
    for (int s = 128; s > 0; s >>= 1) { if (t < s) red[t] = fmaxf(red[t], red[t + s]); __syncthreads(); }
    mx = red[0]; __syncthreads();
    float sum = 0.f;
    for (int l = t; l < LL; l += 256) {
        float e = fexp2((lg[l] - mx) * LOG2E);
        float m = (l < LQ) ? q_mask[b * LQ + l] : r_mask[b * (KK * LR) + l - LQ];
        float em = e * m;
        lg[l] = em;
        sum += em;
    }
    red[t] = sum; __syncthreads();
    for (int s = 128; s > 0; s >>= 1) { if (t < s) red[t] += red[t + s]; __syncthreads(); }
    float inv = 1.f / red[0];
    __syncthreads();
    float* aout = out + B * H + (size_t)b * LL;
    float* cov  = out + B * H + (size_t)B * LL + (size_t)b * LL;
    for (int l = t; l < LL; l += 256) {
        float a = lg[l] * inv;
        aout[l] = a;
        cov[l] = qr_cov[b * LL + l] + a;
        coef[b * LL + l] = a * wbuf[b * LL + l];
    }
}

// ---------------------------------------------------------------- K5b: c_t from fp32 sources
__global__ __launch_bounds__(256) void k5b_ct(
    const float* __restrict__ h_q, const float* __restrict__ h_r,
    const float* __restrict__ coef, float* __restrict__ out) {
    int b = blockIdx.x / 34, chunk = blockIdx.x % 34;
    int t = threadIdx.x;
    int l0 = chunk * 64;
    __shared__ float cl[64];
    __shared__ float red[4][512];
    if (t < 64) cl[t] = coef[b * LL + l0 + t];
    __syncthreads();
    const float* src = (chunk < 2)
        ? h_q + ((size_t)b * LQ + l0) * H
        : h_r + ((size_t)b * (KK * LR) + (l0 - LQ)) * H;
    int rr = t >> 6, lane = t & 63, cc = lane * 8;
    float a[8] = {};
    for (int l = rr; l < 64; l += 4) {
        float c = cl[l];
        float4 x0 = *(const float4*)(src + (size_t)l * H + cc);
        float4 x1 = *(const float4*)(src + (size_t)l * H + cc + 4);
        a[0] += c * x0.x; a[1] += c * x0.y; a[2] += c * x0.z; a[3] += c * x0.w;
        a[4] += c * x1.x; a[5] += c * x1.y; a[6] += c * x1.z; a[7] += c * x1.w;
    }
#pragma unroll
    for (int j = 0; j < 8; ++j) red[rr][cc + j] = a[j];
    __syncthreads();
    int col = t * 2;
    float s0 = red[0][col] + red[1][col] + red[2][col] + red[3][col];
    float s1 = red[0][col + 1] + red[1][col + 1] + red[2][col + 1] + red[3][col + 1];
    atomicAdd(&out[b * H + col], s0);
    atomicAdd(&out[b * H + col + 1], s1);
}

// ================================================================ launch
extern "C" void kernel_launch(void* const* d_in, const int* in_sizes, int n_in,
                              void* d_out, int out_size, void* d_ws, size_t ws_size,
                              hipStream_t stream) {
    (void)in_sizes; (void)n_in; (void)out_size; (void)ws_size;
    const float* h_q    = (const float*)d_in[0];
    const float* q_mask = (const float*)d_in[1];
    const float* h_r    = (const float*)d_in[2];
    const float* r_mask = (const float*)d_in[3];
    const float* s_t    = (const float*)d_in[4];
    const float* qr_cov = (const float*)d_in[5];
    const float* U_w    = (const float*)d_in[6];
    const float* Wc_w   = (const float*)d_in[7];
    const float* Ws_w   = (const float*)d_in[8];
    const float* Wqr_w  = (const float*)d_in[9];
    const float* Wqr_b  = (const float*)d_in[10];
    const float* Vr_w   = (const float*)d_in[11];
    float* out = (float*)d_out;

    char* p = (char*)d_ws;
    unsigned char*  Xb8   = (unsigned char*)p;  p += (size_t)B * LL * H;
    unsigned short* Xq    = (unsigned short*)p; p += (size_t)B * LQ * H * 2;
    unsigned short* Uwb   = (unsigned short*)p; p += (size_t)H * H * 2;
    unsigned char*  Wqrb8 = (unsigned char*)p;  p += (size_t)H * H;
    unsigned char*  hqU8  = (unsigned char*)p;  p += (size_t)B * LQ * H;
    float* sWs       = (float*)p; p += (size_t)B * H * 4;
    float* maxq      = (float*)p; p += (size_t)B * KK * 128 * 4;
    float* maxr_part = (float*)p; p += (size_t)B * KK * 2 * 256 * 4;
    float* wbuf      = (float*)p; p += (size_t)B * LL * 4;
    float* logits    = (float*)p; p += (size_t)B * LL * 4;
    float* coef      = (float*)p; p += (size_t)B * LL * 4;

    k0_convert<<<K0GRID, 256, 0, stream>>>(h_q, h_r, U_w, Wqr_w, Xq, Uwb,
                                           Xb8, Wqrb8, logits, out, wbuf,
                                           s_t, Ws_w, sWs);
    k1_gemm_hqU<<<256, 256, 0, stream>>>(Xq, Uwb, hqU8);
    k2_scores<<<512, 256, 0, stream>>>(hqU8, Xb8, maxq, maxr_part);
    k3_alphas<<<B * KK, 256, 0, stream>>>(maxq, maxr_part, r_mask, q_mask, wbuf);
    k4_gemm_logits<<<8704, 256, 0, stream>>>(
        Xb8, Wqrb8, sWs, Wqr_b, Wc_w, Vr_w, wbuf, qr_cov, logits);
    k5a_softmax<<<B, 256, 0, stream>>>(logits, q_mask, r_mask, qr_cov, wbuf, out, coef);
    k5b_ct<<<B * 34, 256, 0, stream>>>(h_q, h_r, coef, out);
}